// Round 15
// baseline (50.272 us; speedup 1.0000x reference)
//
#include <hip/hip_runtime.h>

// DIAGNOSTIC ROUND: byte-identical r14 kernels; sig_chunk launched TWICE
// (idempotent -> same output, deterministic). dur(this) - dur(r14) ~= chunk time.
// Truncated path signature, trunc=4, D=8, B=128, S=512. NCH=4 chunks of CH=128.

constexpr int Bc = 128, Sc = 512, Tc = 511;
constexpr int NCH = 4, CH = 128;
constexpr int SIGSZ = 8 + 64 + 512 + 4096;        // 4680 floats

// ---------------- Phase 1 inner loop (CB = 4*waveid, compile-time) ----------------
template <int CB>
__device__ __forceinline__ void run_loop(
    const float* __restrict__ dxs, int a, int bcoord,
    float acc4[4][8], float acc3[4], float& s2ab, float& s1a)
{
#pragma unroll 4
    for (int t = 0; t < CH; ++t) {
        const float* rp = &dxs[t * 8];
        float4 lo = *(const float4*)rp;           // broadcast b128
        float4 hi = *(const float4*)(rp + 4);     // broadcast b128
        float r[8] = {lo.x, lo.y, lo.z, lo.w, hi.x, hi.y, hi.z, hi.w};
        float da = rp[a];                         // LDS b32, conflict-free
        float db = rp[bcoord];                    // LDS b32, conflict-free

        float v = fmaf(s1a, 1.f / 6.f, da * (1.f / 24.f));
        float w = fmaf(0.5f, s1a, da * (1.f / 6.f));
        float g = fmaf(db, v, 0.5f * s2ab);       // K_j  = acc3_j + dc_j * g
        float h = fmaf(db, w, s2ab);              // acc3_j += dc_j * h

#pragma unroll
        for (int j = 0; j < 4; ++j) {
            float dc = r[CB + j];                 // compile-time index
            float K = fmaf(dc, g, acc3[j]);
#pragma unroll
            for (int d = 0; d < 8; ++d)
                acc4[j][d] = fmaf(r[d], K, acc4[j][d]);
            acc3[j] = fmaf(dc, h, acc3[j]);
        }
        s2ab = fmaf(s1a, db, fmaf(0.5f * da, db, s2ab));
        s1a += da;
    }
}

// ---------------- Phase 1: per-chunk signature ----------------
__global__ __launch_bounds__(128)
void sig_chunk(const float* __restrict__ path, float* __restrict__ ws) {
    const int blk = blockIdx.x;
    const int b   = blk >> 2;                     // batch
    const int c   = blk & 3;                      // chunk
    const int tid = threadIdx.x;
    const int t0  = c * CH;

    __shared__ __align__(16) float dxs[CH * 8];   // 4 KiB
    {
        const float4* p4 = (const float4*)(path + (((size_t)b * Sc + t0) << 3));
#pragma unroll
        for (int i = tid; i < CH * 2; i += 128) { // CH*2 float4s (each covers half a row)
            float4 v = make_float4(0.f, 0.f, 0.f, 0.f);
            if (t0 + (i >> 1) < Tc) {
                float4 x0 = p4[i];
                float4 x1 = p4[i + 2];
                v = make_float4(x1.x - x0.x, x1.y - x0.y, x1.z - x0.z, x1.w - x0.w);
            }
            ((float4*)dxs)[i] = v;                // tail rows -> 0 (identity)
        }
    }
    __syncthreads();                              // only barrier

    const int half   = tid >> 6;                  // wave id (0/1)
    const int a      = (tid >> 3) & 7;
    const int bcoord = tid & 7;
    const int k      = tid & 63;                  // (a,b) pair index

    float acc4[4][8];
#pragma unroll
    for (int j = 0; j < 4; ++j)
#pragma unroll
        for (int d = 0; d < 8; ++d) acc4[j][d] = 0.f;
    float acc3[4] = {0.f, 0.f, 0.f, 0.f};
    float s2ab = 0.f, s1a = 0.f;

    if (half == 0) run_loop<0>(dxs, a, bcoord, acc4, acc3, s2ab, s1a);
    else           run_loop<4>(dxs, a, bcoord, acc4, acc3, s2ab, s1a);

    // ---- write signature: [s1(8) | s2(64) | s3(512) | s4(4096)] ----
    float* o = ws + (size_t)blk * SIGSZ;
    if (half == 0) {
        if (bcoord == 0) o[a] = s1a;              // level-1 elem a
        o[8 + k] = s2ab;                          // level-2 elem (a,b)
    }
    *(float4*)(o + 72 + k * 8 + half * 4) = make_float4(acc3[0], acc3[1], acc3[2], acc3[3]);
#pragma unroll
    for (int j = 0; j < 4; ++j) {
        float* p4 = o + 584 + k * 64 + (half * 4 + j) * 8;
        *(float4*)(p4)     = make_float4(acc4[j][0], acc4[j][1], acc4[j][2], acc4[j][3]);
        *(float4*)(p4 + 4) = make_float4(acc4[j][4], acc4[j][5], acc4[j][6], acc4[j][7]);
    }
}

// ---------------- Phase 2: fold chunk signatures (LDS-staged) ----------------
__global__ __launch_bounds__(512)
void sig_combine(const float* __restrict__ ws, float* __restrict__ out) {
    const int b = blockIdx.x, tid = threadIdx.x;
    const int aa = tid >> 6, bb = (tid >> 3) & 7, cc = tid & 7;

    __shared__ __align__(16) float ylds[584];     // levels 1-3 of current chunk

    float x4[8] = {0.f, 0.f, 0.f, 0.f, 0.f, 0.f, 0.f, 0.f};
    float x3 = 0.f, x2ab = 0.f, x2own = 0.f;
    float x1a = 0.f, x1b = 0.f, x1c = 0.f;

    for (int c = 0; c < NCH; ++c) {
        const float* y = ws + ((size_t)(b * NCH + c)) * SIGSZ;

        if (tid < 146)
            *(float4*)(ylds + 4 * tid) = *(const float4*)(y + 4 * tid);
        __syncthreads();

        float y1a = ylds[aa], y1b = ylds[bb], y1c = ylds[cc];
        float y2ab = ylds[8 + 8 * aa + bb];
        float y2bc = ylds[8 + 8 * bb + cc];
        float4 y1lo = *(const float4*)ylds;
        float4 y1hi = *(const float4*)(ylds + 4);
        const float* y2r = ylds + 8 + 8 * cc;
        float4 y2lo = *(const float4*)y2r;
        float4 y2hi = *(const float4*)(y2r + 4);
        const float* y3r = ylds + 72 + 8 * (tid & 63);
        float4 y3lo = *(const float4*)y3r;
        float4 y3hi = *(const float4*)(y3r + 4);
        float y3own = ylds[72 + tid];
        const float* y4r = y + 584 + 8 * tid;     // global, per-thread
        float4 y4lo = *(const float4*)y4r;
        float4 y4hi = *(const float4*)(y4r + 4);

        x4[0] = x4[0] + x3 * y1lo.x + x2ab * y2lo.x + x1a * y3lo.x + y4lo.x;
        x4[1] = x4[1] + x3 * y1lo.y + x2ab * y2lo.y + x1a * y3lo.y + y4lo.y;
        x4[2] = x4[2] + x3 * y1lo.z + x2ab * y2lo.z + x1a * y3lo.z + y4lo.z;
        x4[3] = x4[3] + x3 * y1lo.w + x2ab * y2lo.w + x1a * y3lo.w + y4lo.w;
        x4[4] = x4[4] + x3 * y1hi.x + x2ab * y2hi.x + x1a * y3hi.x + y4hi.x;
        x4[5] = x4[5] + x3 * y1hi.y + x2ab * y2hi.y + x1a * y3hi.y + y4hi.y;
        x4[6] = x4[6] + x3 * y1hi.z + x2ab * y2hi.z + x1a * y3hi.z + y4hi.z;
        x4[7] = x4[7] + x3 * y1hi.w + x2ab * y2hi.w + x1a * y3hi.w + y4hi.w;

        x3 = x3 + x2ab * y1c + x1a * y2bc + y3own;
        x2ab  = x2ab  + x1a * y1b + y2ab;
        x2own = x2own + x1b * y1c + y2bc;
        x1a += y1a; x1b += y1b; x1c += y1c;

        __syncthreads();                          // before next chunk's staging
    }

    float* o = out + (size_t)b * SIGSZ;
    if (tid < 8)  o[tid] = x1c;
    if (tid < 64) o[8 + tid] = x2own;
    o[72 + tid] = x3;
    *(float4*)(o + 584 + 8 * tid)     = make_float4(x4[0], x4[1], x4[2], x4[3]);
    *(float4*)(o + 584 + 8 * tid + 4) = make_float4(x4[4], x4[5], x4[6], x4[7]);
}

// ---------------- Fallback (single-kernel, used if ws too small) ----------------
__global__ __launch_bounds__(512)
void sig_fallback(const float* __restrict__ path, float* __restrict__ out) {
    const int b = blockIdx.x, tid = threadIdx.x;
    __shared__ float dxAll[Tc * 8];
    const float* prow = path + (size_t)b * Sc * 8;
    for (int n = tid; n < Tc * 8; n += 512) dxAll[n] = prow[n + 8] - prow[n];
    __syncthreads();

    const int aa = tid >> 6, bb = (tid >> 3) & 7, cc = tid & 7;
    float acc4[8] = {0.f, 0.f, 0.f, 0.f, 0.f, 0.f, 0.f, 0.f};
    float acc3 = 0.f, s2ab = 0.f, acc2 = 0.f, s1a = 0.f, s1b = 0.f, s1c = 0.f;
    for (int t = 0; t < Tc; ++t) {
        const float* r = &dxAll[t * 8];
        float4 lo = *(const float4*)r;
        float4 hi = *(const float4*)(r + 4);
        float da = r[aa], db = r[bb], dc = r[cc];
        float e = db * dc;
        float K = acc3 + s2ab * (0.5f * dc) + e * fmaf(s1a, 1.f / 6.f, da * (1.f / 24.f));
        acc4[0] = fmaf(lo.x, K, acc4[0]);
        acc4[1] = fmaf(lo.y, K, acc4[1]);
        acc4[2] = fmaf(lo.z, K, acc4[2]);
        acc4[3] = fmaf(lo.w, K, acc4[3]);
        acc4[4] = fmaf(hi.x, K, acc4[4]);
        acc4[5] = fmaf(hi.y, K, acc4[5]);
        acc4[6] = fmaf(hi.z, K, acc4[6]);
        acc4[7] = fmaf(hi.w, K, acc4[7]);
        acc3 = acc3 + s2ab * dc + e * fmaf(0.5f, s1a, da * (1.f / 6.f));
        acc2 = fmaf(s1b, dc, fmaf(0.5f, e, acc2));
        s2ab = fmaf(s1a, db, fmaf(0.5f * da, db, s2ab));
        s1a += da; s1b += db; s1c += dc;
    }
    float* o = out + (size_t)b * SIGSZ;
    if (tid < 8)  o[tid] = s1c;
    if (tid < 64) o[8 + tid] = acc2;
    o[72 + tid] = acc3;
    *(float4*)(o + 584 + 8 * tid)     = make_float4(acc4[0], acc4[1], acc4[2], acc4[3]);
    *(float4*)(o + 584 + 8 * tid + 4) = make_float4(acc4[4], acc4[5], acc4[6], acc4[7]);
}

extern "C" void kernel_launch(void* const* d_in, const int* in_sizes, int n_in,
                              void* d_out, int out_size, void* d_ws, size_t ws_size,
                              hipStream_t stream) {
    const float* path = (const float*)d_in[0];
    float* out = (float*)d_out;
    const size_t need = (size_t)Bc * NCH * SIGSZ * sizeof(float);   // ~9.6 MB
    if (ws_size >= need) {
        float* ws = (float*)d_ws;
        // DIAGNOSTIC: chunk launched twice (idempotent); delta vs r14 = chunk time.
        sig_chunk  <<<dim3(Bc * NCH), dim3(128), 0, stream>>>(path, ws);
        sig_chunk  <<<dim3(Bc * NCH), dim3(128), 0, stream>>>(path, ws);
        sig_combine<<<dim3(Bc), dim3(512), 0, stream>>>(ws, out);
    } else {
        sig_fallback<<<dim3(Bc), dim3(512), 0, stream>>>(path, out);
    }
}

// Round 16
// 33.131 us; speedup vs baseline: 1.5174x; 1.5174x over previous
//
#include <hip/hip_runtime.h>

// Truncated path signature, trunc=4, D=8, B=128, S=512.
// Phase 1 (sig_chunk): 1024 blocks (b = blk>>3, c = blk&7), **64 threads =
//   1 wave**. Lane = (a,b digit) owns ALL 8 c's: acc4[8][8], acc3[8], s2ab,
//   s1a. Halves total wave-steps (LDS row tax paid once per chunk-step, not
//   twice) and doubles per-step issue width to hide LDS latency.
//   ~87 VALU/step via g/h factoring; float4 staging; single barrier.
// Phase 2 (sig_combine): r10's proven version -- 128 blocks x 512 thr,
//   levels 1-3 of each chunk staged in LDS, per-thread y4 row from global.
//   Fold order 0..7 (deterministic).

constexpr int Bc = 128, Sc = 512, Tc = 511;
constexpr int NCH = 8, CH = 64;
constexpr int SIGSZ = 8 + 64 + 512 + 4096;        // 4680 floats

// ---------------- Phase 1: per-chunk signature (1 wave, 8 c's per lane) ----------------
__global__ __launch_bounds__(64)
void sig_chunk(const float* __restrict__ path, float* __restrict__ ws) {
    const int blk = blockIdx.x;
    const int b   = blk >> 3;                     // batch
    const int c   = blk & 7;                      // chunk
    const int tid = threadIdx.x;                  // 0..63
    const int t0  = c * CH;

    __shared__ __align__(16) float dxs[CH * 8];   // 2 KiB
    {
        const float4* p4 = (const float4*)(path + (((size_t)b * Sc + t0) << 3));
#pragma unroll
        for (int i = tid; i < CH * 2; i += 64) {  // 128 float4s; i covers half of row i>>1
            float4 v = make_float4(0.f, 0.f, 0.f, 0.f);
            if (t0 + (i >> 1) < Tc) {
                float4 x0 = p4[i];
                float4 x1 = p4[i + 2];
                v = make_float4(x1.x - x0.x, x1.y - x0.y, x1.z - x0.z, x1.w - x0.w);
            }
            ((float4*)dxs)[i] = v;                // tail rows -> 0 (identity)
        }
    }
    __syncthreads();                              // only barrier

    const int a   = tid >> 3;                     // digit a
    const int bco = tid & 7;                      // digit b
    const int k   = tid;                          // (a,b) pair index

    float acc4[8][8];
#pragma unroll
    for (int j = 0; j < 8; ++j)
#pragma unroll
        for (int d = 0; d < 8; ++d) acc4[j][d] = 0.f;
    float acc3[8] = {0.f, 0.f, 0.f, 0.f, 0.f, 0.f, 0.f, 0.f};
    float s2ab = 0.f, s1a = 0.f;

#pragma unroll 2
    for (int t = 0; t < CH; ++t) {
        const float* rp = &dxs[t * 8];
        float4 lo = *(const float4*)rp;           // broadcast b128
        float4 hi = *(const float4*)(rp + 4);     // broadcast b128
        float r[8] = {lo.x, lo.y, lo.z, lo.w, hi.x, hi.y, hi.z, hi.w};
        float da = rp[a];                         // LDS b32, conflict-free
        float db = rp[bco];                       // LDS b32, conflict-free

        float v = fmaf(s1a, 1.f / 6.f, da * (1.f / 24.f));
        float w = fmaf(0.5f, s1a, da * (1.f / 6.f));
        float g = fmaf(db, v, 0.5f * s2ab);       // K_j  = acc3_j + dc_j * g
        float h = fmaf(db, w, s2ab);              // acc3_j += dc_j * h

#pragma unroll
        for (int j = 0; j < 8; ++j) {
            float dc = r[j];                      // compile-time index
            float K = fmaf(dc, g, acc3[j]);
#pragma unroll
            for (int d = 0; d < 8; ++d)
                acc4[j][d] = fmaf(r[d], K, acc4[j][d]);
            acc3[j] = fmaf(dc, h, acc3[j]);
        }
        s2ab = fmaf(s1a, db, fmaf(0.5f * da, db, s2ab));
        s1a += da;
    }

    // ---- write signature: [s1(8) | s2(64) | s3(512) | s4(4096)] ----
    float* o = ws + (size_t)blk * SIGSZ;
    if (bco == 0) o[a] = s1a;                     // level-1 elem a
    o[8 + k] = s2ab;                              // level-2 elem (a,b)
    *(float4*)(o + 72 + k * 8)     = make_float4(acc3[0], acc3[1], acc3[2], acc3[3]);
    *(float4*)(o + 72 + k * 8 + 4) = make_float4(acc3[4], acc3[5], acc3[6], acc3[7]);
#pragma unroll
    for (int j = 0; j < 8; ++j) {
        float* p4 = o + 584 + k * 64 + j * 8;
        *(float4*)(p4)     = make_float4(acc4[j][0], acc4[j][1], acc4[j][2], acc4[j][3]);
        *(float4*)(p4 + 4) = make_float4(acc4[j][4], acc4[j][5], acc4[j][6], acc4[j][7]);
    }
}

// ---------------- Phase 2: fold chunk signatures (r10, LDS-staged) ----------------
__global__ __launch_bounds__(512)
void sig_combine(const float* __restrict__ ws, float* __restrict__ out) {
    const int b = blockIdx.x, tid = threadIdx.x;
    const int aa = tid >> 6, bb = (tid >> 3) & 7, cc = tid & 7;

    __shared__ __align__(16) float ylds[584];     // levels 1-3 of current chunk

    float x4[8] = {0.f, 0.f, 0.f, 0.f, 0.f, 0.f, 0.f, 0.f};
    float x3 = 0.f, x2ab = 0.f, x2own = 0.f;
    float x1a = 0.f, x1b = 0.f, x1c = 0.f;

    for (int c = 0; c < NCH; ++c) {
        const float* y = ws + ((size_t)(b * NCH + c)) * SIGSZ;

        if (tid < 146)
            *(float4*)(ylds + 4 * tid) = *(const float4*)(y + 4 * tid);
        __syncthreads();

        float y1a = ylds[aa], y1b = ylds[bb], y1c = ylds[cc];
        float y2ab = ylds[8 + 8 * aa + bb];
        float y2bc = ylds[8 + 8 * bb + cc];
        float4 y1lo = *(const float4*)ylds;
        float4 y1hi = *(const float4*)(ylds + 4);
        const float* y2r = ylds + 8 + 8 * cc;
        float4 y2lo = *(const float4*)y2r;
        float4 y2hi = *(const float4*)(y2r + 4);
        const float* y3r = ylds + 72 + 8 * (tid & 63);
        float4 y3lo = *(const float4*)y3r;
        float4 y3hi = *(const float4*)(y3r + 4);
        float y3own = ylds[72 + tid];
        const float* y4r = y + 584 + 8 * tid;     // global, per-thread
        float4 y4lo = *(const float4*)y4r;
        float4 y4hi = *(const float4*)(y4r + 4);

        x4[0] = x4[0] + x3 * y1lo.x + x2ab * y2lo.x + x1a * y3lo.x + y4lo.x;
        x4[1] = x4[1] + x3 * y1lo.y + x2ab * y2lo.y + x1a * y3lo.y + y4lo.y;
        x4[2] = x4[2] + x3 * y1lo.z + x2ab * y2lo.z + x1a * y3lo.z + y4lo.z;
        x4[3] = x4[3] + x3 * y1lo.w + x2ab * y2lo.w + x1a * y3lo.w + y4lo.w;
        x4[4] = x4[4] + x3 * y1hi.x + x2ab * y2hi.x + x1a * y3hi.x + y4hi.x;
        x4[5] = x4[5] + x3 * y1hi.y + x2ab * y2hi.y + x1a * y3hi.y + y4hi.y;
        x4[6] = x4[6] + x3 * y1hi.z + x2ab * y2hi.z + x1a * y3hi.z + y4hi.z;
        x4[7] = x4[7] + x3 * y1hi.w + x2ab * y2hi.w + x1a * y3hi.w + y4hi.w;

        x3 = x3 + x2ab * y1c + x1a * y2bc + y3own;
        x2ab  = x2ab  + x1a * y1b + y2ab;
        x2own = x2own + x1b * y1c + y2bc;
        x1a += y1a; x1b += y1b; x1c += y1c;

        __syncthreads();                          // before next chunk's staging
    }

    float* o = out + (size_t)b * SIGSZ;
    if (tid < 8)  o[tid] = x1c;
    if (tid < 64) o[8 + tid] = x2own;
    o[72 + tid] = x3;
    *(float4*)(o + 584 + 8 * tid)     = make_float4(x4[0], x4[1], x4[2], x4[3]);
    *(float4*)(o + 584 + 8 * tid + 4) = make_float4(x4[4], x4[5], x4[6], x4[7]);
}

// ---------------- Fallback (single-kernel, used if ws too small) ----------------
__global__ __launch_bounds__(512)
void sig_fallback(const float* __restrict__ path, float* __restrict__ out) {
    const int b = blockIdx.x, tid = threadIdx.x;
    __shared__ float dxAll[Tc * 8];
    const float* prow = path + (size_t)b * Sc * 8;
    for (int n = tid; n < Tc * 8; n += 512) dxAll[n] = prow[n + 8] - prow[n];
    __syncthreads();

    const int aa = tid >> 6, bb = (tid >> 3) & 7, cc = tid & 7;
    float acc4[8] = {0.f, 0.f, 0.f, 0.f, 0.f, 0.f, 0.f, 0.f};
    float acc3 = 0.f, s2ab = 0.f, acc2 = 0.f, s1a = 0.f, s1b = 0.f, s1c = 0.f;
    for (int t = 0; t < Tc; ++t) {
        const float* r = &dxAll[t * 8];
        float4 lo = *(const float4*)r;
        float4 hi = *(const float4*)(r + 4);
        float da = r[aa], db = r[bb], dc = r[cc];
        float e = db * dc;
        float K = acc3 + s2ab * (0.5f * dc) + e * fmaf(s1a, 1.f / 6.f, da * (1.f / 24.f));
        acc4[0] = fmaf(lo.x, K, acc4[0]);
        acc4[1] = fmaf(lo.y, K, acc4[1]);
        acc4[2] = fmaf(lo.z, K, acc4[2]);
        acc4[3] = fmaf(lo.w, K, acc4[3]);
        acc4[4] = fmaf(hi.x, K, acc4[4]);
        acc4[5] = fmaf(hi.y, K, acc4[5]);
        acc4[6] = fmaf(hi.z, K, acc4[6]);
        acc4[7] = fmaf(hi.w, K, acc4[7]);
        acc3 = acc3 + s2ab * dc + e * fmaf(0.5f, s1a, da * (1.f / 6.f));
        acc2 = fmaf(s1b, dc, fmaf(0.5f, e, acc2));
        s2ab = fmaf(s1a, db, fmaf(0.5f * da, db, s2ab));
        s1a += da; s1b += db; s1c += dc;
    }
    float* o = out + (size_t)b * SIGSZ;
    if (tid < 8)  o[tid] = s1c;
    if (tid < 64) o[8 + tid] = acc2;
    o[72 + tid] = acc3;
    *(float4*)(o + 584 + 8 * tid)     = make_float4(acc4[0], acc4[1], acc4[2], acc4[3]);
    *(float4*)(o + 584 + 8 * tid + 4) = make_float4(acc4[4], acc4[5], acc4[6], acc4[7]);
}

extern "C" void kernel_launch(void* const* d_in, const int* in_sizes, int n_in,
                              void* d_out, int out_size, void* d_ws, size_t ws_size,
                              hipStream_t stream) {
    const float* path = (const float*)d_in[0];
    float* out = (float*)d_out;
    const size_t need = (size_t)Bc * NCH * SIGSZ * sizeof(float);   // ~19.2 MB
    if (ws_size >= need) {
        float* ws = (float*)d_ws;
        sig_chunk  <<<dim3(Bc * NCH), dim3(64), 0, stream>>>(path, ws);
        sig_combine<<<dim3(Bc), dim3(512), 0, stream>>>(ws, out);
    } else {
        sig_fallback<<<dim3(Bc), dim3(512), 0, stream>>>(path, out);
    }
}

// Round 17
// 29.963 us; speedup vs baseline: 1.6778x; 1.1057x over previous
//
#include <hip/hip_runtime.h>

// Truncated path signature, trunc=4, D=8, B=128, S=512.
// Phase 1 (sig_chunk): UNCHANGED from r14 (proven 30.4-30.8 us config):
//   512 blocks (b = blk>>2, c = blk&3), 128 thr (2 waves), NCH=4, CH=128.
//   Lane = (a,b digit); wave id selects c-range {4h..4h+3} via template<CB>.
//   51 VALU/step via g/h factoring; float4 staging; single barrier.
// Phase 2 (sig_combine): REWORKED -- 512 blocks (4 slices/batch x 128 thr),
//   BARRIER-FREE, no LDS: all y-terms direct global loads (LLC-served).
//   Zero barriers -> compiler pipelines all 4 chunk iterations' loads.
//   Fold order 0..3 (deterministic).

constexpr int Bc = 128, Sc = 512, Tc = 511;
constexpr int NCH = 4, CH = 128;
constexpr int SIGSZ = 8 + 64 + 512 + 4096;        // 4680 floats

// ---------------- Phase 1 inner loop (CB = 4*waveid, compile-time) ----------------
template <int CB>
__device__ __forceinline__ void run_loop(
    const float* __restrict__ dxs, int a, int bcoord,
    float acc4[4][8], float acc3[4], float& s2ab, float& s1a)
{
#pragma unroll 4
    for (int t = 0; t < CH; ++t) {
        const float* rp = &dxs[t * 8];
        float4 lo = *(const float4*)rp;           // broadcast b128
        float4 hi = *(const float4*)(rp + 4);     // broadcast b128
        float r[8] = {lo.x, lo.y, lo.z, lo.w, hi.x, hi.y, hi.z, hi.w};
        float da = rp[a];                         // LDS b32, conflict-free
        float db = rp[bcoord];                    // LDS b32, conflict-free

        float v = fmaf(s1a, 1.f / 6.f, da * (1.f / 24.f));
        float w = fmaf(0.5f, s1a, da * (1.f / 6.f));
        float g = fmaf(db, v, 0.5f * s2ab);       // K_j  = acc3_j + dc_j * g
        float h = fmaf(db, w, s2ab);              // acc3_j += dc_j * h

#pragma unroll
        for (int j = 0; j < 4; ++j) {
            float dc = r[CB + j];                 // compile-time index
            float K = fmaf(dc, g, acc3[j]);
#pragma unroll
            for (int d = 0; d < 8; ++d)
                acc4[j][d] = fmaf(r[d], K, acc4[j][d]);
            acc3[j] = fmaf(dc, h, acc3[j]);
        }
        s2ab = fmaf(s1a, db, fmaf(0.5f * da, db, s2ab));
        s1a += da;
    }
}

// ---------------- Phase 1: per-chunk signature ----------------
__global__ __launch_bounds__(128)
void sig_chunk(const float* __restrict__ path, float* __restrict__ ws) {
    const int blk = blockIdx.x;
    const int b   = blk >> 2;                     // batch
    const int c   = blk & 3;                      // chunk
    const int tid = threadIdx.x;
    const int t0  = c * CH;

    __shared__ __align__(16) float dxs[CH * 8];   // 4 KiB
    {
        const float4* p4 = (const float4*)(path + (((size_t)b * Sc + t0) << 3));
#pragma unroll
        for (int i = tid; i < CH * 2; i += 128) { // CH*2 float4s (each covers half a row)
            float4 v = make_float4(0.f, 0.f, 0.f, 0.f);
            if (t0 + (i >> 1) < Tc) {
                float4 x0 = p4[i];
                float4 x1 = p4[i + 2];
                v = make_float4(x1.x - x0.x, x1.y - x0.y, x1.z - x0.z, x1.w - x0.w);
            }
            ((float4*)dxs)[i] = v;                // tail rows -> 0 (identity)
        }
    }
    __syncthreads();                              // only barrier

    const int half   = tid >> 6;                  // wave id (0/1)
    const int a      = (tid >> 3) & 7;
    const int bcoord = tid & 7;
    const int k      = tid & 63;                  // (a,b) pair index

    float acc4[4][8];
#pragma unroll
    for (int j = 0; j < 4; ++j)
#pragma unroll
        for (int d = 0; d < 8; ++d) acc4[j][d] = 0.f;
    float acc3[4] = {0.f, 0.f, 0.f, 0.f};
    float s2ab = 0.f, s1a = 0.f;

    if (half == 0) run_loop<0>(dxs, a, bcoord, acc4, acc3, s2ab, s1a);
    else           run_loop<4>(dxs, a, bcoord, acc4, acc3, s2ab, s1a);

    // ---- write signature: [s1(8) | s2(64) | s3(512) | s4(4096)] ----
    float* o = ws + (size_t)blk * SIGSZ;
    if (half == 0) {
        if (bcoord == 0) o[a] = s1a;              // level-1 elem a
        o[8 + k] = s2ab;                          // level-2 elem (a,b)
    }
    *(float4*)(o + 72 + k * 8 + half * 4) = make_float4(acc3[0], acc3[1], acc3[2], acc3[3]);
#pragma unroll
    for (int j = 0; j < 4; ++j) {
        float* p4 = o + 584 + k * 64 + (half * 4 + j) * 8;
        *(float4*)(p4)     = make_float4(acc4[j][0], acc4[j][1], acc4[j][2], acc4[j][3]);
        *(float4*)(p4 + 4) = make_float4(acc4[j][4], acc4[j][5], acc4[j][6], acc4[j][7]);
    }
}

// ---------------- Phase 2: fold chunk signatures (barrier-free, global-direct) ----------------
// Grid: Bc * 4 blocks of 128 threads; block slice q handles tg = q*128 + tid.
__global__ __launch_bounds__(128)
void sig_combine(const float* __restrict__ ws, float* __restrict__ out) {
    const int blk = blockIdx.x;
    const int b   = blk >> 2;
    const int tg  = ((blk & 3) << 7) | threadIdx.x;   // global tid in [0,512)
    const int aa = tg >> 6, bb = (tg >> 3) & 7, cc = tg & 7;

    float x4[8] = {0.f, 0.f, 0.f, 0.f, 0.f, 0.f, 0.f, 0.f};
    float x3 = 0.f, x2ab = 0.f, x2own = 0.f;
    float x1a = 0.f, x1b = 0.f, x1c = 0.f;

#pragma unroll
    for (int c = 0; c < NCH; ++c) {
        const float* y = ws + ((size_t)(b * NCH + c)) * SIGSZ;

        float y1a = y[aa], y1b = y[bb], y1c = y[cc];
        float y2ab = y[8 + 8 * aa + bb];
        float y2bc = y[8 + 8 * bb + cc];
        float4 y1lo = *(const float4*)y;
        float4 y1hi = *(const float4*)(y + 4);
        const float* y2r = y + 8 + 8 * cc;
        float4 y2lo = *(const float4*)y2r;
        float4 y2hi = *(const float4*)(y2r + 4);
        const float* y3r = y + 72 + 8 * (tg & 63);
        float4 y3lo = *(const float4*)y3r;
        float4 y3hi = *(const float4*)(y3r + 4);
        float y3own = y[72 + tg];
        const float* y4r = y + 584 + 8 * tg;
        float4 y4lo = *(const float4*)y4r;
        float4 y4hi = *(const float4*)(y4r + 4);

        x4[0] = x4[0] + x3 * y1lo.x + x2ab * y2lo.x + x1a * y3lo.x + y4lo.x;
        x4[1] = x4[1] + x3 * y1lo.y + x2ab * y2lo.y + x1a * y3lo.y + y4lo.y;
        x4[2] = x4[2] + x3 * y1lo.z + x2ab * y2lo.z + x1a * y3lo.z + y4lo.z;
        x4[3] = x4[3] + x3 * y1lo.w + x2ab * y2lo.w + x1a * y3lo.w + y4lo.w;
        x4[4] = x4[4] + x3 * y1hi.x + x2ab * y2hi.x + x1a * y3hi.x + y4hi.x;
        x4[5] = x4[5] + x3 * y1hi.y + x2ab * y2hi.y + x1a * y3hi.y + y4hi.y;
        x4[6] = x4[6] + x3 * y1hi.z + x2ab * y2hi.z + x1a * y3hi.z + y4hi.z;
        x4[7] = x4[7] + x3 * y1hi.w + x2ab * y2hi.w + x1a * y3hi.w + y4hi.w;

        x3 = x3 + x2ab * y1c + x1a * y2bc + y3own;
        x2ab  = x2ab  + x1a * y1b + y2ab;
        x2own = x2own + x1b * y1c + y2bc;
        x1a += y1a; x1b += y1b; x1c += y1c;
    }

    float* o = out + (size_t)b * SIGSZ;
    if (tg < 8)  o[tg] = x1c;
    if (tg < 64) o[8 + tg] = x2own;
    o[72 + tg] = x3;
    *(float4*)(o + 584 + 8 * tg)     = make_float4(x4[0], x4[1], x4[2], x4[3]);
    *(float4*)(o + 584 + 8 * tg + 4) = make_float4(x4[4], x4[5], x4[6], x4[7]);
}

// ---------------- Fallback (single-kernel, used if ws too small) ----------------
__global__ __launch_bounds__(512)
void sig_fallback(const float* __restrict__ path, float* __restrict__ out) {
    const int b = blockIdx.x, tid = threadIdx.x;
    __shared__ float dxAll[Tc * 8];
    const float* prow = path + (size_t)b * Sc * 8;
    for (int n = tid; n < Tc * 8; n += 512) dxAll[n] = prow[n + 8] - prow[n];
    __syncthreads();

    const int aa = tid >> 6, bb = (tid >> 3) & 7, cc = tid & 7;
    float acc4[8] = {0.f, 0.f, 0.f, 0.f, 0.f, 0.f, 0.f, 0.f};
    float acc3 = 0.f, s2ab = 0.f, acc2 = 0.f, s1a = 0.f, s1b = 0.f, s1c = 0.f;
    for (int t = 0; t < Tc; ++t) {
        const float* r = &dxAll[t * 8];
        float4 lo = *(const float4*)r;
        float4 hi = *(const float4*)(r + 4);
        float da = r[aa], db = r[bb], dc = r[cc];
        float e = db * dc;
        float K = acc3 + s2ab * (0.5f * dc) + e * fmaf(s1a, 1.f / 6.f, da * (1.f / 24.f));
        acc4[0] = fmaf(lo.x, K, acc4[0]);
        acc4[1] = fmaf(lo.y, K, acc4[1]);
        acc4[2] = fmaf(lo.z, K, acc4[2]);
        acc4[3] = fmaf(lo.w, K, acc4[3]);
        acc4[4] = fmaf(hi.x, K, acc4[4]);
        acc4[5] = fmaf(hi.y, K, acc4[5]);
        acc4[6] = fmaf(hi.z, K, acc4[6]);
        acc4[7] = fmaf(hi.w, K, acc4[7]);
        acc3 = acc3 + s2ab * dc + e * fmaf(0.5f, s1a, da * (1.f / 6.f));
        acc2 = fmaf(s1b, dc, fmaf(0.5f, e, acc2));
        s2ab = fmaf(s1a, db, fmaf(0.5f * da, db, s2ab));
        s1a += da; s1b += db; s1c += dc;
    }
    float* o = out + (size_t)b * SIGSZ;
    if (tid < 8)  o[tid] = s1c;
    if (tid < 64) o[8 + tid] = acc2;
    o[72 + tid] = acc3;
    *(float4*)(o + 584 + 8 * tid)     = make_float4(acc4[0], acc4[1], acc4[2], acc4[3]);
    *(float4*)(o + 584 + 8 * tid + 4) = make_float4(acc4[4], acc4[5], acc4[6], acc4[7]);
}

extern "C" void kernel_launch(void* const* d_in, const int* in_sizes, int n_in,
                              void* d_out, int out_size, void* d_ws, size_t ws_size,
                              hipStream_t stream) {
    const float* path = (const float*)d_in[0];
    float* out = (float*)d_out;
    const size_t need = (size_t)Bc * NCH * SIGSZ * sizeof(float);   // ~9.6 MB
    if (ws_size >= need) {
        float* ws = (float*)d_ws;
        sig_chunk  <<<dim3(Bc * NCH), dim3(128), 0, stream>>>(path, ws);
        sig_combine<<<dim3(Bc * 4), dim3(128), 0, stream>>>(ws, out);
    } else {
        sig_fallback<<<dim3(Bc), dim3(512), 0, stream>>>(path, out);
    }
}